// Round 1
// baseline (1117.037 us; speedup 1.0000x reference)
//
#include <hip/hip_runtime.h>
#include <stdint.h>

#define T_TOKENS 8192
#define K_IN 4096
#define N_OUT 12288

using int32x4 = __attribute__((ext_vector_type(4))) int;

// ---------------- Kernel 1: per-token symmetric int8 quant ----------------
// One block (256 thr) per token row of 4096 fp32. absmax -> scale -> rintf(x/scale).
__global__ void quant_rows(const float* __restrict__ x,
                           int8_t* __restrict__ xq,
                           float* __restrict__ xs) {
    const int t = blockIdx.x;
    const int tid = threadIdx.x;
    const float* row = x + (size_t)t * K_IN;
    float4 v[4];
    float am = 0.0f;
#pragma unroll
    for (int i = 0; i < 4; ++i) {
        v[i] = ((const float4*)row)[tid + 256 * i];
        am = fmaxf(am, fmaxf(fmaxf(fabsf(v[i].x), fabsf(v[i].y)),
                             fmaxf(fabsf(v[i].z), fabsf(v[i].w))));
    }
#pragma unroll
    for (int off = 32; off > 0; off >>= 1)
        am = fmaxf(am, __shfl_xor(am, off));
    __shared__ float red[4];
    if ((tid & 63) == 0) red[tid >> 6] = am;
    __syncthreads();
    am = fmaxf(fmaxf(red[0], red[1]), fmaxf(red[2], red[3]));
    const float scale = fmaxf(am, 1e-8f) / 127.0f;  // matches reference x_scale
    if (tid == 0) xs[t] = scale;
    char4* dst = (char4*)(xq + (size_t)t * K_IN);
#pragma unroll
    for (int i = 0; i < 4; ++i) {
        float4 f = v[i];
        char4 c;
        float r;
        r = fminf(fmaxf(rintf(f.x / scale), -127.0f), 127.0f); c.x = (signed char)(int)r;
        r = fminf(fmaxf(rintf(f.y / scale), -127.0f), 127.0f); c.y = (signed char)(int)r;
        r = fminf(fmaxf(rintf(f.z / scale), -127.0f), 127.0f); c.z = (signed char)(int)r;
        r = fminf(fmaxf(rintf(f.w / scale), -127.0f), 127.0f); c.w = (signed char)(int)r;
        dst[tid + 256 * i] = c;
    }
}

// ---------------- Kernel 2: pack int32 weight -> int8 ----------------
// Harness delivers integer inputs as int32; repack to dense int8 [N_OUT][K_IN].
__global__ void pack_weight(const int* __restrict__ w, int8_t* __restrict__ wq) {
    const int idx = blockIdx.x * 256 + threadIdx.x;  // one per 4 ints, grid exact
    int4 v = ((const int4*)w)[idx];
    char4 c;
    c.x = (signed char)v.x; c.y = (signed char)v.y;
    c.z = (signed char)v.z; c.w = (signed char)v.w;
    ((char4*)wq)[idx] = c;
}

// ---------------- Kernel 3: int8 GEMM + fused dequant epilogue ----------------
// C[m][n] = sum_k A[m][k]*W[n][k]; out = acc*xs[m]*wsc[n]+bias[n].
// 128x128 block tile, BK=64, 4 waves in 2x2, each 64x64 via 4x4 mfma_i32_16x16x64_i8.
// LDS staged with global_load_lds width=16; XOR kblock swizzle (kb ^ (row>>1)&3)
// -> ds_read_b128 fragment reads hit all 32 banks (2 lanes/bank = free).
__global__ __launch_bounds__(256) void gemm_i8(
        const int8_t* __restrict__ Aq, const int8_t* __restrict__ Bq,
        const float* __restrict__ xs, const float* __restrict__ wsc,
        const float* __restrict__ bias, float* __restrict__ out) {
    __shared__ __align__(16) int8_t smA[128 * 64];
    __shared__ __align__(16) int8_t smB[128 * 64];
    const int tid  = threadIdx.x;
    const int lane = tid & 63;
    const int w    = tid >> 6;
    const int m0   = blockIdx.y * 128;
    const int n0   = blockIdx.x * 128;
    const int wm   = (w >> 1) * 64;
    const int wn   = (w & 1) * 64;
    const int fr   = lane & 15;   // fragment row (A: m, B: n)
    const int q    = lane >> 4;   // k quad: bytes q*16..q*16+15

    int32x4 acc[4][4] = {};

    // Staging geometry (constant across K loop): 2 issues each for A and B.
    int flati[2], rowi[2], kbsi[2];
#pragma unroll
    for (int i = 0; i < 2; ++i) {
        const int flat = i * 4096 + w * 1024 + lane * 16;
        const int row  = flat >> 6;
        const int kb   = (flat >> 4) & 3;
        flati[i] = flat;
        rowi[i]  = row;
        kbsi[i]  = (kb ^ ((row >> 1) & 3)) * 16;  // source kblock after swizzle
    }

    for (int k0 = 0; k0 < K_IN; k0 += 64) {
#pragma unroll
        for (int i = 0; i < 2; ++i) {
            const int8_t* ga = Aq + (size_t)(m0 + rowi[i]) * K_IN + k0 + kbsi[i];
            const int8_t* gb = Bq + (size_t)(n0 + rowi[i]) * K_IN + k0 + kbsi[i];
            __builtin_amdgcn_global_load_lds(
                (const __attribute__((address_space(1))) void*)ga,
                (__attribute__((address_space(3))) void*)(&smA[flati[i]]), 16, 0, 0);
            __builtin_amdgcn_global_load_lds(
                (const __attribute__((address_space(1))) void*)gb,
                (__attribute__((address_space(3))) void*)(&smB[flati[i]]), 16, 0, 0);
        }
        __syncthreads();

        int32x4 af[4], bf[4];
#pragma unroll
        for (int im = 0; im < 4; ++im) {
            const int r  = wm + im * 16 + fr;
            const int kb = q ^ ((r >> 1) & 3);
            af[im] = *(const int32x4*)&smA[r * 64 + kb * 16];
        }
#pragma unroll
        for (int in = 0; in < 4; ++in) {
            const int r  = wn + in * 16 + fr;
            const int kb = q ^ ((r >> 1) & 3);
            bf[in] = *(const int32x4*)&smB[r * 64 + kb * 16];
        }
#pragma unroll
        for (int im = 0; im < 4; ++im)
#pragma unroll
            for (int in = 0; in < 4; ++in)
                acc[im][in] = __builtin_amdgcn_mfma_i32_16x16x64_i8(
                    af[im], bf[in], acc[im][in], 0, 0, 0);
        __syncthreads();
    }

    // Epilogue: C/D layout col=lane&15, row=q*4+reg (verified m89/m91, dtype-indep).
#pragma unroll
    for (int im = 0; im < 4; ++im) {
#pragma unroll
        for (int i = 0; i < 4; ++i) {
            const int m = m0 + wm + im * 16 + q * 4 + i;
            const float sa = xs[m];
            float* orow = out + (size_t)m * N_OUT + n0;
#pragma unroll
            for (int in = 0; in < 4; ++in) {
                const int n = wn + in * 16 + fr;
                orow[n] = (float)acc[im][in][i] * sa * wsc[n0 + n] + bias[n0 + n];
            }
        }
    }
}

extern "C" void kernel_launch(void* const* d_in, const int* in_sizes, int n_in,
                              void* d_out, int out_size, void* d_ws, size_t ws_size,
                              hipStream_t stream) {
    const float* x    = (const float*)d_in[0];
    const int*   wgt  = (const int*)d_in[1];     // int8 values widened to int32
    const float* wsc  = (const float*)d_in[2];   // [N_OUT]
    const float* bias = (const float*)d_in[3];   // [N_OUT]
    float* out = (float*)d_out;

    uint8_t* ws = (uint8_t*)d_ws;
    float*  xs = (float*)ws;                                   // 8192 f32 = 32 KB
    int8_t* xq = (int8_t*)(ws + 32768);                        // 33.55 MB
    int8_t* wq = (int8_t*)(ws + 32768 + (size_t)T_TOKENS * K_IN);  // 50.33 MB

    hipLaunchKernelGGL(pack_weight,
                       dim3(((size_t)N_OUT * K_IN) / 4 / 256), dim3(256), 0, stream,
                       wgt, wq);
    hipLaunchKernelGGL(quant_rows, dim3(T_TOKENS), dim3(256), 0, stream, x, xq, xs);
    hipLaunchKernelGGL(gemm_i8, dim3(N_OUT / 128, T_TOKENS / 128), dim3(256), 0, stream,
                       xq, wq, xs, wsc, bias, out);
}